// Round 3
// baseline (252.118 us; speedup 1.0000x reference)
//
#include <hip/hip_runtime.h>
#include <hip/hip_cooperative_groups.h>

namespace cg = cooperative_groups;

#define B       1024
#define NI      64
#define NN      8256
#define E_EDGES 131072
#define N_OUT   64

#define CAP1    16     // max input-edges (src<NI) per row; mean 0.12 -> hugely safe
#define CAP2    96     // max edges per dst<64 row; mean ~16 -> hugely safe
#define WCAP    4096   // worklist capacity; expected ~1008 distinct rows
#define GRID    512    // 2 blocks/CU on 256 CUs -> trivially co-resident
#define TPB     256

// Single cooperative kernel, 4 phases separated by grid.sync():
//  P0: zero bookkeeping, transpose inputs [B,NI] -> inputsT [NI,B]
//  P1: one edge/thread: has_in mask, pass-1 input-edge slabs, pass-2 slabs,
//      dedup worklist of state1 rows pass 2 will read
//  P2: pass 1 (state0 = 0 so only src<NI edges contribute), ONLY worklist rows
//  P3: pass 2, 64 output rows, writes d_out directly (transposed scatter)
__global__ __launch_bounds__(TPB, 4) void mega_kernel(
    const float* __restrict__ inputs,    // [B, NI]
    const float* __restrict__ weights,   // [E]
    const float* __restrict__ bias,      // [NN]
    const float* __restrict__ response,  // [NN]
    const int* __restrict__ src,         // [E]
    const int* __restrict__ dst,         // [E]
    float* __restrict__ out,             // [B, N_OUT]
    float* __restrict__ inputsT,         // [NI, B]
    float* __restrict__ state1T,         // [NN, B] (only worklist rows written)
    int* __restrict__ hasIn,             // [NN]
    int* __restrict__ cntIn,             // [NN]
    int* __restrict__ colIn,             // [NN, CAP1]
    float* __restrict__ valIn,           // [NN, CAP1]
    int* __restrict__ flags,             // [NN]
    int* __restrict__ cnt2,              // [64]
    int* __restrict__ col2,              // [64, CAP2]
    float* __restrict__ val2,            // [64, CAP2]
    int* __restrict__ worklist,          // [WCAP]
    int* __restrict__ nWork)             // [1]
{
    cg::grid_group grid = cg::this_grid();
    const int tid = blockIdx.x * TPB + threadIdx.x;   // 0 .. GRID*TPB-1 (=131072)

    // ---- P0: init + transpose ----
    if (tid < NN) { hasIn[tid] = 0; cntIn[tid] = 0; flags[tid] = 0; }
    if (tid < 64) cnt2[tid] = 0;
    if (tid == 0) *nWork = 0;
    if (tid < NI * B) {
        int s = tid / B, b = tid % B;
        inputsT[tid] = inputs[b * NI + s];
    }
    grid.sync();

    // ---- P1: edge scan (exactly one edge per thread) ----
    if (tid < E_EDGES) {
        int s = src[tid], d = dst[tid];
        float wt = weights[tid];
        hasIn[d] = 1;  // idempotent
        if (s < NI) {
            int p = atomicAdd(&cntIn[d], 1);
            if (p < CAP1) { colIn[d * CAP1 + p] = s; valIn[d * CAP1 + p] = wt; }
        }
        if (d < 64) {
            int p = atomicAdd(&cnt2[d], 1);
            if (p < CAP2) { col2[d * CAP2 + p] = s; val2[d * CAP2 + p] = wt; }
            if (s >= NI) {
                int n = s - NI;
                if (atomicExch(&flags[n], 1) == 0) {
                    int q = atomicAdd(nWork, 1);
                    if (q < WCAP) worklist[q] = n;
                }
            }
        }
    }
    grid.sync();

    // ---- P2: pass 1 over worklist rows only ----
    {
        int nw = *nWork; if (nw > WCAP) nw = WCAP;
        int b = threadIdx.x * 4;
        for (int w = blockIdx.x; w < nw; w += gridDim.x) {
            int n = worklist[w];
            float4 o = make_float4(0.f, 0.f, 0.f, 0.f);
            if (hasIn[n]) {
                int cnt = cntIn[n]; if (cnt > CAP1) cnt = CAP1;
                float4 acc = make_float4(0.f, 0.f, 0.f, 0.f);
                for (int e = 0; e < cnt; ++e) {
                    int s = colIn[n * CAP1 + e];
                    float wt = valIn[n * CAP1 + e];
                    float4 v = *(const float4*)(inputsT + (size_t)s * B + b);
                    acc.x = fmaf(wt, v.x, acc.x);
                    acc.y = fmaf(wt, v.y, acc.y);
                    acc.z = fmaf(wt, v.z, acc.z);
                    acc.w = fmaf(wt, v.w, acc.w);
                }
                float bi = bias[n], rr = response[n];
                o.x = tanhf(fmaf(rr, acc.x, bi));
                o.y = tanhf(fmaf(rr, acc.y, bi));
                o.z = tanhf(fmaf(rr, acc.z, bi));
                o.w = tanhf(fmaf(rr, acc.w, bi));
            }
            *(float4*)(state1T + (size_t)n * B + b) = o;
        }
    }
    grid.sync();

    // ---- P3: pass 2, rows 0..63, write out[b*N_OUT+n] directly ----
    if (blockIdx.x < N_OUT) {
        int n = blockIdx.x;
        int b = threadIdx.x * 4;
        float4 o = make_float4(0.f, 0.f, 0.f, 0.f);
        if (hasIn[n]) {
            int cnt = cnt2[n]; if (cnt > CAP2) cnt = CAP2;
            float4 acc = make_float4(0.f, 0.f, 0.f, 0.f);
            for (int e = 0; e < cnt; ++e) {
                int s = col2[n * CAP2 + e];
                float wt = val2[n * CAP2 + e];
                const float* row = (s < NI) ? (inputsT + (size_t)s * B)
                                            : (state1T + (size_t)(s - NI) * B);
                float4 v = *(const float4*)(row + b);
                acc.x = fmaf(wt, v.x, acc.x);
                acc.y = fmaf(wt, v.y, acc.y);
                acc.z = fmaf(wt, v.z, acc.z);
                acc.w = fmaf(wt, v.w, acc.w);
            }
            float bi = bias[n], rr = response[n];
            o.x = tanhf(fmaf(rr, acc.x, bi));
            o.y = tanhf(fmaf(rr, acc.y, bi));
            o.z = tanhf(fmaf(rr, acc.z, bi));
            o.w = tanhf(fmaf(rr, acc.w, bi));
        }
        out[(size_t)(b + 0) * N_OUT + n] = o.x;
        out[(size_t)(b + 1) * N_OUT + n] = o.y;
        out[(size_t)(b + 2) * N_OUT + n] = o.z;
        out[(size_t)(b + 3) * N_OUT + n] = o.w;
    }
}

extern "C" void kernel_launch(void* const* d_in, const int* in_sizes, int n_in,
                              void* d_out, int out_size, void* d_ws, size_t ws_size,
                              hipStream_t stream) {
    const float* inputs   = (const float*)d_in[0];
    const float* weights  = (const float*)d_in[1];
    const float* bias     = (const float*)d_in[2];
    const float* response = (const float*)d_in[3];
    const int*   src_idx  = (const int*)d_in[4];
    const int*   dst_idx  = (const int*)d_in[5];
    float* out = (float*)d_out;

    char* ws = (char*)d_ws;
    size_t off = 0;
    auto alloc = [&](size_t bytes) -> void* {
        void* p = ws + off;
        off = (off + bytes + 255) & ~(size_t)255;
        return p;
    };
    float* inputsT  = (float*)alloc((size_t)NI * B * sizeof(float));
    float* state1T  = (float*)alloc((size_t)NN * B * sizeof(float));
    int*   hasIn    = (int*)alloc(NN * sizeof(int));
    int*   cntIn    = (int*)alloc(NN * sizeof(int));
    int*   flags    = (int*)alloc(NN * sizeof(int));
    int*   cnt2     = (int*)alloc(64 * sizeof(int));
    int*   colIn    = (int*)alloc((size_t)NN * CAP1 * sizeof(int));
    float* valIn    = (float*)alloc((size_t)NN * CAP1 * sizeof(float));
    int*   col2     = (int*)alloc((size_t)64 * CAP2 * sizeof(int));
    float* val2     = (float*)alloc((size_t)64 * CAP2 * sizeof(float));
    int*   worklist = (int*)alloc(WCAP * sizeof(int));
    int*   nWork    = (int*)alloc(sizeof(int));

    void* args[] = {
        (void*)&inputs, (void*)&weights, (void*)&bias, (void*)&response,
        (void*)&src_idx, (void*)&dst_idx, (void*)&out,
        (void*)&inputsT, (void*)&state1T,
        (void*)&hasIn, (void*)&cntIn, (void*)&colIn, (void*)&valIn,
        (void*)&flags, (void*)&cnt2, (void*)&col2, (void*)&val2,
        (void*)&worklist, (void*)&nWork
    };
    hipLaunchCooperativeKernel((void*)mega_kernel, dim3(GRID), dim3(TPB),
                               args, 0, stream);
}

// Round 4
// 96.304 us; speedup vs baseline: 2.6179x; 2.6179x over previous
//
#include <hip/hip_runtime.h>

#define B       1024
#define NI      64
#define NN      8256
#define E_EDGES 131072
#define N_OUT   64

#define CAP1    16     // max input-edges (src<NI) per row; mean 0.123 -> P(>16) ~ 1e-20
#define CAP2    96     // max edges per dst<64 row; mean ~15.9 -> P(>96) astronomically small

// K1: zero bookkeeping + transpose inputs [B,NI] -> inputsT [NI,B].
// grid 256 x 256 = 65536 threads = NI*B.
__global__ __launch_bounds__(256) void init_kernel(
    const float* __restrict__ inputs,
    float* __restrict__ inputsT,
    int* __restrict__ hasIn, int* __restrict__ cntIn, int* __restrict__ cnt2) {
    int tid = blockIdx.x * 256 + threadIdx.x;
    if (tid < NN) { hasIn[tid] = 0; cntIn[tid] = 0; }
    if (tid < 64) cnt2[tid] = 0;
    // tid = s*B + b
    int s = tid >> 10, b = tid & 1023;
    inputsT[tid] = inputs[b * NI + s];
}

// K2: one edge per thread:
//  - hasIn[dst] = 1 (idempotent store)
//  - src<NI  -> append to per-row input-edge slab (pass-1 contribution)
//  - dst<64  -> append to pass-2 slab
__global__ __launch_bounds__(256) void edges_kernel(
    const int* __restrict__ src, const int* __restrict__ dst,
    const float* __restrict__ w,
    int* __restrict__ hasIn,
    int* __restrict__ cntIn, int* __restrict__ colIn, float* __restrict__ valIn,
    int* __restrict__ cnt2, int* __restrict__ col2, float* __restrict__ val2) {
    int e = blockIdx.x * 256 + threadIdx.x;
    if (e >= E_EDGES) return;
    int s = src[e], d = dst[e];
    float wt = w[e];
    hasIn[d] = 1;
    if (s < NI) {
        int p = atomicAdd(&cntIn[d], 1);
        if (p < CAP1) { colIn[d * CAP1 + p] = s; valIn[d * CAP1 + p] = wt; }
    }
    if (d < 64) {
        int p = atomicAdd(&cnt2[d], 1);
        if (p < CAP2) { col2[d * CAP2 + p] = s; val2[d * CAP2 + p] = wt; }
    }
}

// K3: pass 2 with inline recompute of pass-1 values (state0 = 0, so a state-1
// row is tanh(bias + resp * sum over its src<NI edges) — avg 0.12 edges/row).
// grid = 64 rows x 4 batch chunks = 256 blocks; thread owns one batch element.
__global__ __launch_bounds__(256) void out_kernel(
    const float* __restrict__ inputsT,   // [NI, B]
    const int* __restrict__ hasIn,
    const int* __restrict__ cntIn, const int* __restrict__ colIn, const float* __restrict__ valIn,
    const int* __restrict__ cnt2, const int* __restrict__ col2, const float* __restrict__ val2,
    const float* __restrict__ bias, const float* __restrict__ response,
    float* __restrict__ out)             // [B, N_OUT]
{
    int n = blockIdx.x & 63;                       // output row (wave-uniform)
    int b = ((blockIdx.x >> 6) << 8) + threadIdx.x;  // batch element
    float o = 0.f;
    if (hasIn[n]) {
        int cnt = cnt2[n]; if (cnt > CAP2) cnt = CAP2;
        float acc = 0.f;
        for (int e = 0; e < cnt; ++e) {
            int s = col2[n * CAP2 + e];            // scalar load (uniform)
            float wt = val2[n * CAP2 + e];
            float v;
            if (s < NI) {
                v = inputsT[s * B + b];            // coalesced
            } else {
                int m = s - NI;
                v = 0.f;
                if (hasIn[m]) {
                    int c1 = cntIn[m]; if (c1 > CAP1) c1 = CAP1;
                    float a1 = 0.f;
                    for (int j = 0; j < c1; ++j) {
                        int sj = colIn[m * CAP1 + j];
                        a1 = fmaf(valIn[m * CAP1 + j], inputsT[sj * B + b], a1);
                    }
                    v = tanhf(fmaf(response[m], a1, bias[m]));
                }
            }
            o = fmaf(wt, v, o);
        }
        o = tanhf(fmaf(response[n], o, bias[n]));
    }
    out[(size_t)b * N_OUT + n] = o;
}

extern "C" void kernel_launch(void* const* d_in, const int* in_sizes, int n_in,
                              void* d_out, int out_size, void* d_ws, size_t ws_size,
                              hipStream_t stream) {
    const float* inputs   = (const float*)d_in[0];
    const float* weights  = (const float*)d_in[1];
    const float* bias     = (const float*)d_in[2];
    const float* response = (const float*)d_in[3];
    const int*   src_idx  = (const int*)d_in[4];
    const int*   dst_idx  = (const int*)d_in[5];
    float* out = (float*)d_out;

    char* ws = (char*)d_ws;
    size_t off = 0;
    auto alloc = [&](size_t bytes) -> void* {
        void* p = ws + off;
        off = (off + bytes + 255) & ~(size_t)255;
        return p;
    };
    float* inputsT = (float*)alloc((size_t)NI * B * sizeof(float));
    int*   hasIn   = (int*)alloc(NN * sizeof(int));
    int*   cntIn   = (int*)alloc(NN * sizeof(int));
    int*   cnt2    = (int*)alloc(64 * sizeof(int));
    int*   colIn   = (int*)alloc((size_t)NN * CAP1 * sizeof(int));
    float* valIn   = (float*)alloc((size_t)NN * CAP1 * sizeof(float));
    int*   col2    = (int*)alloc((size_t)64 * CAP2 * sizeof(int));
    float* val2    = (float*)alloc((size_t)64 * CAP2 * sizeof(float));

    init_kernel<<<(NI * B) / 256, 256, 0, stream>>>(inputs, inputsT, hasIn, cntIn, cnt2);
    edges_kernel<<<E_EDGES / 256, 256, 0, stream>>>(src_idx, dst_idx, weights,
                                                    hasIn, cntIn, colIn, valIn,
                                                    cnt2, col2, val2);
    out_kernel<<<256, 256, 0, stream>>>(inputsT, hasIn, cntIn, colIn, valIn,
                                        cnt2, col2, val2, bias, response, out);
}

// Round 5
// 94.780 us; speedup vs baseline: 2.6600x; 1.0161x over previous
//
#include <hip/hip_runtime.h>

#define B       1024
#define NI      64
#define NN      8256
#define E_EDGES 131072
#define N_OUT   64

#define CAP1    16     // max input-edges (src<NI) per row; mean 0.123 -> P(>CAP1) ~ 1e-20
#define CAP2    96     // max edges per dst<64 row; mean ~15.9 -> P(>CAP2) astronomically small

// K1: one edge per thread (plus NN spare lanes precompute T[m] = tanh(bias[m])):
//  - hasIn[dst] = 1 (idempotent store)
//  - src<NI  -> append to per-row input-edge slab (pass-1 contribution)
//  - dst<64  -> append to pass-2 slab
// Counters (hasIn/cntIn/cnt2) are zeroed by a preceding hipMemsetAsync node.
__global__ __launch_bounds__(256) void edges_kernel(
    const int* __restrict__ src, const int* __restrict__ dst,
    const float* __restrict__ w, const float* __restrict__ bias,
    int* __restrict__ hasIn,
    int* __restrict__ cntIn, int* __restrict__ colIn, float* __restrict__ valIn,
    int* __restrict__ cnt2, int* __restrict__ col2, float* __restrict__ val2,
    float* __restrict__ T) {
    int tid = blockIdx.x * 256 + threadIdx.x;
    if (tid < NN) T[tid] = tanhf(bias[tid]);   // batch-uniform pass-1 value (0 input edges case)
    if (tid >= E_EDGES) return;
    int s = src[tid], d = dst[tid];
    float wt = w[tid];
    hasIn[d] = 1;
    if (s < NI) {
        int p = atomicAdd(&cntIn[d], 1);
        if (p < CAP1) { colIn[d * CAP1 + p] = s; valIn[d * CAP1 + p] = wt; }
    }
    if (d < 64) {
        int p = atomicAdd(&cnt2[d], 1);
        if (p < CAP2) { col2[d * CAP2 + p] = s; val2[d * CAP2 + p] = wt; }
    }
}

// K2: pass 2 with inline pass-1 values. state0 = 0, so a state-1 row is
// tanh(bias + resp * sum over its src<NI edges); with 0 input edges (the
// ~99.9% case) that's the precomputed batch-uniform T[m].
// grid = 64 rows x 4 batch chunks; thread owns one (row, batch-element) pair.
__global__ __launch_bounds__(256) void out_kernel(
    const float* __restrict__ inputs,    // [B, NI]
    const int* __restrict__ hasIn,
    const int* __restrict__ cntIn, const int* __restrict__ colIn, const float* __restrict__ valIn,
    const int* __restrict__ cnt2, const int* __restrict__ col2, const float* __restrict__ val2,
    const float* __restrict__ bias, const float* __restrict__ response,
    const float* __restrict__ T,
    float* __restrict__ out)             // [B, N_OUT]
{
    int n = blockIdx.x & 63;                         // output row (wave-uniform)
    int b = ((blockIdx.x >> 6) << 8) + threadIdx.x;  // batch element
    float o = 0.f;
    if (hasIn[n]) {
        int cnt = cnt2[n]; if (cnt > CAP2) cnt = CAP2;
        for (int e = 0; e < cnt; ++e) {
            int s = col2[n * CAP2 + e];              // wave-uniform scalar load
            float wt = val2[n * CAP2 + e];
            float v;
            if (s < NI) {
                v = inputs[b * NI + s];              // rare (~1/130): strided gather, L2-hit
            } else {
                int m = s - NI;
                v = 0.f;
                if (hasIn[m]) {
                    int c1 = cntIn[m];
                    if (c1 == 0) {
                        v = T[m];                    // batch-uniform: scalar table lookup
                    } else {
                        if (c1 > CAP1) c1 = CAP1;
                        float a1 = 0.f;
                        for (int j = 0; j < c1; ++j) {
                            int sj = colIn[m * CAP1 + j];
                            a1 = fmaf(valIn[m * CAP1 + j], inputs[b * NI + sj], a1);
                        }
                        v = tanhf(fmaf(response[m], a1, bias[m]));
                    }
                }
            }
            o = fmaf(wt, v, o);
        }
        o = tanhf(fmaf(response[n], o, bias[n]));
    }
    out[(size_t)b * N_OUT + n] = o;
}

extern "C" void kernel_launch(void* const* d_in, const int* in_sizes, int n_in,
                              void* d_out, int out_size, void* d_ws, size_t ws_size,
                              hipStream_t stream) {
    const float* inputs   = (const float*)d_in[0];
    const float* weights  = (const float*)d_in[1];
    const float* bias     = (const float*)d_in[2];
    const float* response = (const float*)d_in[3];
    const int*   src_idx  = (const int*)d_in[4];
    const int*   dst_idx  = (const int*)d_in[5];
    float* out = (float*)d_out;

    char* ws = (char*)d_ws;
    // Counters first, contiguous, so ONE small memset node zeroes them all.
    int*   hasIn = (int*)ws;                    // [NN]
    int*   cntIn = hasIn + NN;                  // [NN]
    int*   cnt2  = cntIn + NN;                  // [64]
    size_t off = ((size_t)(2 * NN + 64) * sizeof(int) + 255) & ~(size_t)255;
    auto alloc = [&](size_t bytes) -> void* {
        void* p = ws + off;
        off = (off + bytes + 255) & ~(size_t)255;
        return p;
    };
    float* T     = (float*)alloc((size_t)NN * sizeof(float));
    int*   colIn = (int*)alloc((size_t)NN * CAP1 * sizeof(int));
    float* valIn = (float*)alloc((size_t)NN * CAP1 * sizeof(float));
    int*   col2  = (int*)alloc((size_t)64 * CAP2 * sizeof(int));
    float* val2  = (float*)alloc((size_t)64 * CAP2 * sizeof(float));

    hipMemsetAsync(hasIn, 0, (size_t)(2 * NN + 64) * sizeof(int), stream);
    edges_kernel<<<E_EDGES / 256, 256, 0, stream>>>(src_idx, dst_idx, weights, bias,
                                                    hasIn, cntIn, colIn, valIn,
                                                    cnt2, col2, val2, T);
    out_kernel<<<256, 256, 0, stream>>>(inputs, hasIn, cntIn, colIn, valIn,
                                        cnt2, col2, val2, bias, response, T, out);
}